// Round 12
// baseline (300.234 us; speedup 1.0000x reference)
//
#include <hip/hip_runtime.h>

typedef short bf16x8 __attribute__((ext_vector_type(8)));
typedef float f32x4  __attribute__((ext_vector_type(4)));

#define N_USER 50000
#define N_ITEM 100000
#define N_NODES 150000
#define EMB 64
#define NNZ 2400000
#define BATCH 4096
#define NSAMP (3 * BATCH)     // 12288 sampled rows
#define NB 512                // row-range buckets (512*293 = 150016 >= 150000)
#define RPB 293               // rows per bucket
#define BS_GRID 500           // edge-slice blocks (NNZ/500 = 4800 exact)
#define EPB (NNZ / BS_GRID)   // 4800 edges per block
#define CAP 5312              // bucket capacity (mean 4687.5 + ~9 sigma)

// bf16 round-to-nearest-even; low 16 bits hold the bf16
__device__ __forceinline__ unsigned int bf16_rne(float x) {
    unsigned int u = __float_as_uint(x);
    return (u + 0x7fffu + ((u >> 16) & 1u)) >> 16;
}
__device__ __forceinline__ float bflo(unsigned int u) { return __uint_as_float(u << 16); }
__device__ __forceinline__ float bfhi(unsigned int u) { return __uint_as_float(u & 0xffff0000u); }

__device__ __forceinline__ void fma8(float v, const uint4& x, float* acc) {
    acc[0] = fmaf(v, bflo(x.x), acc[0]); acc[1] = fmaf(v, bfhi(x.x), acc[1]);
    acc[2] = fmaf(v, bflo(x.y), acc[2]); acc[3] = fmaf(v, bfhi(x.y), acc[3]);
    acc[4] = fmaf(v, bflo(x.z), acc[4]); acc[5] = fmaf(v, bfhi(x.z), acc[5]);
    acc[6] = fmaf(v, bflo(x.w), acc[6]); acc[7] = fmaf(v, bfhi(x.w), acc[7]);
}
__device__ __forceinline__ uint4 pack8(const float* f) {
    return make_uint4((bf16_rne(f[1]) << 16) | bf16_rne(f[0]),
                      (bf16_rne(f[3]) << 16) | bf16_rne(f[2]),
                      (bf16_rne(f[5]) << 16) | bf16_rne(f[4]),
                      (bf16_rne(f[7]) << 16) | bf16_rne(f[6]));
}
__device__ __forceinline__ uint2 cvt2(const float4& v) {
    return make_uint2((bf16_rne(v.y) << 16) | bf16_rne(v.x),
                      (bf16_rne(v.w) << 16) | bf16_rne(v.z));
}

// ==== FUSED scat_init: blocks 0..499 = LDS-sort bin_scatter (NO global atomics);
//      blocks 500.. = streaming init (ego cast / gather0 / W-pack / bias / samp) ====
#define SEG_A (N_NODES * 4)           // 600000 threads: 4x float4 -> 4x uint2 each
#define SEG_B (NSAMP * 16)            // 196608 threads: float4 gather0 each
#define SEG_C (3 * 8192)              // 24576 threads: W bf16 pack (wT[n][k], stride 136)
#define SEG_D 192                     // bias precompute
#define INIT_TOT (SEG_A + SEG_B + SEG_C + SEG_D + NSAMP)
#define INIT_BLOCKS ((INIT_TOT + 1023) / 1024)
__global__ __launch_bounds__(1024) void scat_init(const int* __restrict__ rows,
                                                  const int* __restrict__ cols,
                                                  const float* __restrict__ vals,
                                                  int* __restrict__ gcur,
                                                  int2* __restrict__ tmp_cv,
                                                  const float4* __restrict__ ue4,
                                                  const float4* __restrict__ ie4,
                                                  const int* __restrict__ users,
                                                  const int* __restrict__ pos,
                                                  const int* __restrict__ neg,
                                                  uint2* __restrict__ ego_bf,
                                                  float* __restrict__ out,
                                                  int* __restrict__ samp,
                                                  const float* __restrict__ Wgc,
                                                  const float* __restrict__ Wbi,
                                                  const float* __restrict__ bgc,
                                                  const float* __restrict__ bbi,
                                                  ushort* __restrict__ wbf,
                                                  float* __restrict__ biasf) {
    __shared__ int2 sorted[EPB];                       // 38.4 KB
    __shared__ int hist[NB];
    __shared__ int excl[NB];                           // inclusive after scan
    __shared__ int cur[NB];
    __shared__ int gb[NB];
    const int t = threadIdx.x;
    if (blockIdx.x < BS_GRID) {                        // ---- bin_scatter branch ----
        const int blk = blockIdx.x;
        if (t < NB) { hist[t] = 0; cur[t] = 0; }
        __syncthreads();
        const int e0 = blk * EPB;
        // pass A: bucket histogram
        for (int i = t; i < EPB; i += 1024) atomicAdd(&hist[rows[e0 + i] / RPB], 1);
        __syncthreads();
        // reserve global space per bucket (order across blocks arbitrary)
        if (t < NB) gb[t] = atomicAdd(&gcur[t], hist[t]);
        // scan hist -> inclusive in excl
        if (t < NB) excl[t] = hist[t];
        for (int off = 1; off < NB; off <<= 1) {
            __syncthreads();
            int add = (t < NB && t >= off) ? excl[t - off] : 0;
            __syncthreads();
            if (t < NB) excl[t] += add;
        }
        __syncthreads();
        // pass B: scatter into LDS sorted-by-bucket (rows re-read: L1-hot)
        for (int i = t; i < EPB; i += 1024) {
            int e = e0 + i;
            int r = rows[e];
            int b = r / RPB;
            int slot = atomicAdd(&cur[b], 1);
            unsigned vv = (__float_as_uint(vals[e]) & ~1023u) | (unsigned)(r - b * RPB);
            sorted[excl[b] - hist[b] + slot] = make_int2(cols[e], (int)vv);
        }
        __syncthreads();
        // pass C: wave per bucket, contiguous coalesced flush
        const int w = t >> 6, lane = t & 63;
        for (int b = w; b < NB; b += 16) {
            int lo = excl[b] - hist[b];
            int n = hist[b];
            int2* dst = tmp_cv + (size_t)b * CAP + gb[b];
            for (int k = lane; k < n; k += 64) dst[k] = sorted[lo + k];
        }
        return;
    }
    // ---- streaming init branch ----
    int idx = (blockIdx.x - BS_GRID) * 1024 + t;
    if (idx >= INIT_TOT) return;
    if (idx < SEG_A) {
        const int NU4 = N_USER * 16;                   // 800000 float4s (mult of 4)
        int b4 = idx * 4;
        float4 a, b, c, d;
        if (b4 < NU4) { a = ue4[b4]; b = ue4[b4 + 1]; c = ue4[b4 + 2]; d = ue4[b4 + 3]; }
        else { int j = b4 - NU4; a = ie4[j]; b = ie4[j + 1]; c = ie4[j + 2]; d = ie4[j + 3]; }
        uint2 o0 = cvt2(a), o1 = cvt2(b), o2 = cvt2(c), o3 = cvt2(d);
        uint4* e4 = (uint4*)ego_bf;
        e4[idx * 2]     = make_uint4(o0.x, o0.y, o1.x, o1.y);
        e4[idx * 2 + 1] = make_uint4(o2.x, o2.y, o3.x, o3.y);
    } else if (idx < SEG_A + SEG_B) {
        int tt = idx - SEG_A;
        int r = tt >> 4, dq = tt & 15;
        int seg = r >> 12, bi = r & (BATCH - 1);
        int node = (seg == 0) ? users[bi] : N_USER + ((seg == 1) ? pos[bi] : neg[bi]);
        float4 v = (node < N_USER) ? ue4[node * 16 + dq] : ie4[(node - N_USER) * 16 + dq];
        ((float4*)out)[(size_t)r * 64 + dq] = v;
    } else if (idx < SEG_A + SEG_B + SEG_C) {
        int tt = idx - SEG_A - SEG_B;                  // l*8192 + k*64 + n (coalesced reads)
        int l = tt >> 13, rem = tt & 8191;
        int k = rem >> 6, n = rem & 63;
        float w = (k < 64) ? Wgc[l * 4096 + k * 64 + n] : Wbi[l * 4096 + (k - 64) * 64 + n];
        wbf[l * 8704 + n * 136 + k] = (ushort)bf16_rne(w);
    } else if (idx < SEG_A + SEG_B + SEG_C + SEG_D) {
        int tt = idx - SEG_A - SEG_B - SEG_C;
        biasf[tt] = bgc[tt] + bbi[tt];
    } else {
        int tt = idx - SEG_A - SEG_B - SEG_C - SEG_D;  // < NSAMP
        int seg = tt >> 12, bi = tt & (BATCH - 1);
        samp[tt] = (seg == 0) ? users[bi] : N_USER + ((seg == 1) ? pos[bi] : neg[bi]);
    }
}

// ======== csr_spmm1: bucket row-sort in LDS + ecv flush + LAYER-1 spmm+gemm fused ========
// Edges never leave LDS for layer 1: sorted2 holds the row-sorted bucket; spmm reads
// edge (col,val) via 8-lane broadcast ds_read; ego gathers 4-deep in flight.
// 16 waves = 4 groups x 4 waves; each group = one 32-row spmm_gemm tile per pass (3 passes).
__global__ __launch_bounds__(1024) void csr_spmm1(const int* __restrict__ gcur,
                                                  const int2* __restrict__ tmp_cv,
                                                  int2* __restrict__ ecv,
                                                  int2* __restrict__ row_se,
                                                  const uint4* __restrict__ ego_bf,
                                                  const ushort* __restrict__ wbf,   // layer-0 [64][136]
                                                  const float* __restrict__ biasf,  // layer-0 [64]
                                                  ushort* __restrict__ ego_out,
                                                  float* __restrict__ inv_norm) {
    __shared__ int2 stage[CAP];                        // 42.5 KB raw bucket
    __shared__ int2 sorted2[CAP];                      // 42.5 KB row-sorted
    __shared__ ushort As3[4][32][136];                 // 34.8 KB (per-group A tiles)
    __shared__ int sstart[RPB + 1];
    __shared__ int rcurs[RPB];
    __shared__ int sc[1024];
    const int b = blockIdx.x, t = threadIdx.x;
    const int row0 = b * RPB;
    const int beg = b * CAP;
    const int cnt = gcur[b];
    int lim = N_NODES - row0;
    if (lim > RPB) lim = RPB;

    if (t < RPB) rcurs[t] = 0;
    __syncthreads();
    // load bucket + per-row histogram (single global pass)
    for (int i = t; i < cnt; i += 1024) {
        int2 rec = tmp_cv[beg + i];
        stage[i] = rec;
        atomicAdd(&rcurs[rec.y & 1023], 1);
    }
    __syncthreads();
    int v = (t < RPB) ? rcurs[t] : 0;
    sc[t] = v;
    for (int off = 1; off < 1024; off <<= 1) {
        __syncthreads();
        int add = (t >= off) ? sc[t - off] : 0;
        __syncthreads();
        sc[t] += add;
    }
    __syncthreads();
    int ex = sc[t] - v;                                // exclusive prefix within bucket
    if (t <= RPB) sstart[t] = ex;                      // sstart[RPB] == cnt
    if (t < lim) row_se[row0 + t] = make_int2(beg + ex, beg + ex + v);
    if (t < RPB) rcurs[t] = ex;                        // reuse as permute cursor
    __syncthreads();
    // permute stage -> sorted2 (row-sorted, cleaned val)
    for (int i = t; i < cnt; i += 1024) {
        int2 rec = stage[i];
        int dst = atomicAdd(&rcurs[rec.y & 1023], 1);
        sorted2[dst] = make_int2(rec.x, rec.y & ~1023);
    }
    __syncthreads();
    // coalesced ecv flush for layers 2-3 (stores drain under the spmm below)
    for (int i = t; i < cnt; i += 1024) ecv[beg + i] = sorted2[i];

    // ---- layer-1 spmm + gemm from LDS ----
    const int w = t >> 6, lane = t & 63;
    const int g = w >> 2, wig = w & 3;                 // group 0..3, wave-in-group 0..3
    const int d8 = lane & 7, rl = lane >> 3;
    const int trow = wig * 8 + rl;                     // 0..31 within group tile
    const int l15 = lane & 15, quad = lane >> 4;
    const bf16x8* wt8 = (const bf16x8*)wbf;            // n-row stride 136/8 = 17

    for (int pass = 0; pass < 3; ++pass) {
        int brow = pass * 128 + g * 32 + trow;         // bucket-local row
        bool valid = (brow < lim);
        int s0 = 0, s1 = 0;
        if (valid) { s0 = sstart[brow]; s1 = sstart[brow + 1]; }
        float acc[8] = {0.f, 0.f, 0.f, 0.f, 0.f, 0.f, 0.f, 0.f};
        int j = s0;
        for (; j + 4 <= s1; j += 4) {                  // 4 gathers in flight
            int2 e0 = sorted2[j], e1 = sorted2[j + 1], e2 = sorted2[j + 2], e3 = sorted2[j + 3];
            uint4 x0 = ego_bf[(size_t)e0.x * 8 + d8];
            uint4 x1 = ego_bf[(size_t)e1.x * 8 + d8];
            uint4 x2 = ego_bf[(size_t)e2.x * 8 + d8];
            uint4 x3 = ego_bf[(size_t)e3.x * 8 + d8];
            fma8(__int_as_float(e0.y), x0, acc);
            fma8(__int_as_float(e1.y), x1, acc);
            fma8(__int_as_float(e2.y), x2, acc);
            fma8(__int_as_float(e3.y), x3, acc);
        }
        for (; j < s1; ++j) {
            int2 e = sorted2[j];
            uint4 x = ego_bf[(size_t)e.x * 8 + d8];
            fma8(__int_as_float(e.y), x, acc);
        }
        int node = row0 + (valid ? brow : 0);
        uint4 selfv = ego_bf[(size_t)node * 8 + d8];
        float cs[8] = { bflo(selfv.x) * acc[0], bfhi(selfv.x) * acc[1],
                        bflo(selfv.y) * acc[2], bfhi(selfv.y) * acc[3],
                        bflo(selfv.z) * acc[4], bfhi(selfv.z) * acc[5],
                        bflo(selfv.w) * acc[6], bfhi(selfv.w) * acc[7] };
        *(uint4*)&As3[g][trow][d8 * 8]      = pack8(acc);
        *(uint4*)&As3[g][trow][64 + d8 * 8] = pack8(cs);
        __syncthreads();

        if (wig < 2) {                                 // 2 GEMM waves per group
            const int arow = wig * 16 + l15;
            f32x4 C[4] = {{0,0,0,0}, {0,0,0,0}, {0,0,0,0}, {0,0,0,0}};
#pragma unroll
            for (int ks = 0; ks < 4; ++ks) {
                bf16x8 afr = *(const bf16x8*)&As3[g][arow][(ks * 4 + quad) * 8];
                bf16x8 b0 = wt8[(0 * 16 + l15) * 17 + ks * 4 + quad];
                bf16x8 b1 = wt8[(1 * 16 + l15) * 17 + ks * 4 + quad];
                bf16x8 b2 = wt8[(2 * 16 + l15) * 17 + ks * 4 + quad];
                bf16x8 b3 = wt8[(3 * 16 + l15) * 17 + ks * 4 + quad];
                C[0] = __builtin_amdgcn_mfma_f32_16x16x32_bf16(afr, b0, C[0], 0, 0, 0);
                C[1] = __builtin_amdgcn_mfma_f32_16x16x32_bf16(afr, b1, C[1], 0, 0, 0);
                C[2] = __builtin_amdgcn_mfma_f32_16x16x32_bf16(afr, b2, C[2], 0, 0, 0);
                C[3] = __builtin_amdgcn_mfma_f32_16x16x32_bf16(afr, b3, C[3], 0, 0, 0);
            }
            float x[4][4];
            float ss[4] = {0.f, 0.f, 0.f, 0.f};
#pragma unroll
            for (int nt = 0; nt < 4; ++nt)
#pragma unroll
                for (int rg = 0; rg < 4; ++rg) {
                    float vv = C[nt][rg] + biasf[nt * 16 + l15];
                    vv = (vv >= 0.f) ? vv : 0.2f * vv;
                    x[nt][rg] = vv;
                    ss[rg] = fmaf(vv, vv, ss[rg]);
                }
#pragma unroll
            for (int rg = 0; rg < 4; ++rg) {
                ss[rg] += __shfl_xor(ss[rg], 1);
                ss[rg] += __shfl_xor(ss[rg], 2);
                ss[rg] += __shfl_xor(ss[rg], 4);
                ss[rg] += __shfl_xor(ss[rg], 8);
            }
#pragma unroll
            for (int rg = 0; rg < 4; ++rg) {
                int bro = pass * 128 + g * 32 + wig * 16 + quad * 4 + rg;
                if (bro >= lim) continue;
                int grow = row0 + bro;
                float invr = 1.0f / fmaxf(sqrtf(ss[rg]), 1e-12f);
#pragma unroll
                for (int nt = 0; nt < 4; ++nt)
                    ego_out[(size_t)grow * 64 + nt * 16 + l15] = (ushort)bf16_rne(x[nt][rg]);
                if (l15 == 0) inv_norm[grow] = invr;
            }
        }
        __syncthreads();                               // As reused next pass
    }
}

// ======== FUSED spmm + gemm (proven shape, byte-identical): layers 2-3 ========
__global__ __launch_bounds__(256) void spmm_gemm(const int2* __restrict__ row_se,
                                                 const int2* __restrict__ ecv,
                                                 const uint4* __restrict__ ego_bf, // 8 uint4/row
                                                 const ushort* __restrict__ wbf,   // [64][136] bf16
                                                 const float* __restrict__ biasf,  // [64]
                                                 ushort* __restrict__ ego_out,
                                                 float* __restrict__ inv_norm,
                                                 float* __restrict__ out,
                                                 const int* __restrict__ node_list,
                                                 int n_rows, int out_mode, int col0,
                                                 const ushort* __restrict__ g_ego,
                                                 const float* __restrict__ g_inv,
                                                 const int* __restrict__ g_samp,
                                                 int g_col0) {
    const int t = threadIdx.x;
    const int spmmBlocks = (n_rows + 31) >> 5;
    if ((int)blockIdx.x >= spmmBlocks) {               // ---- piggy slice gather ----
        int i = (blockIdx.x - spmmBlocks) * 256 + t;   // grid sized to exactly NSAMP*EMB
        int r = i >> 6, d = i & 63;
        int node = g_samp[r];
        float v = __uint_as_float(((unsigned int)g_ego[(size_t)node * 64 + d]) << 16) * g_inv[node];
        out[(size_t)r * 256 + g_col0 + d] = v;
        return;
    }

    __shared__ ushort As[32][136];                     // 8.7 KB, padded stride (272 B)

    const int d8 = t & 7;                              // dim group: dims d8*8 .. d8*8+7
    const int rl = t >> 3;                             // local row 0..31
    const int r = blockIdx.x * 32 + rl;
    const bool valid = (r < n_rows);
    const int node = valid ? (node_list ? node_list[r] : r) : 0;
    int s0 = 0, s1 = 0;
    if (valid) { int2 se = row_se[node]; s0 = se.x; s1 = se.y; }
    const uint4 selfv = ego_bf[(size_t)node * 8 + d8];
    const int lbase = (t & 63) & 56;                   // base lane of this 8-lane group

    float acc[8] = {0.f, 0.f, 0.f, 0.f, 0.f, 0.f, 0.f, 0.f};
    int2 m = make_int2(0, 0);
    if (s0 + d8 < s1) m = ecv[s0 + d8];
    for (int e0 = s0; e0 < s1; e0 += 8) {
        int2 mn = make_int2(0, 0);                     // prefetch next packet
        if (e0 + 8 + d8 < s1) mn = ecv[e0 + 8 + d8];
#pragma unroll
        for (int j = 0; j < 8; ++j) {
            int   c = __shfl(m.x, lbase + j);
            float v = __int_as_float(__shfl(m.y, lbase + j));
            const uint4 x = ego_bf[(size_t)c * 8 + d8];
            fma8(v, x, acc);
        }
        m = mn;
    }
    float cs[8] = { bflo(selfv.x) * acc[0], bfhi(selfv.x) * acc[1],
                    bflo(selfv.y) * acc[2], bfhi(selfv.y) * acc[3],
                    bflo(selfv.z) * acc[4], bfhi(selfv.z) * acc[5],
                    bflo(selfv.w) * acc[6], bfhi(selfv.w) * acc[7] };
    *(uint4*)&As[rl][d8 * 8]      = pack8(acc);        // side half (k 0..63)
    *(uint4*)&As[rl][64 + d8 * 8] = pack8(cs);         // ego*side half (k 64..127)
    __syncthreads();

    const int wv = t >> 6;
    if (wv >= 2) return;                               // waves 2,3 done (gemm tail is tiny)
    const int lane = t & 63;
    const int l15 = lane & 15, quad = lane >> 4;
    const bf16x8* wt8 = (const bf16x8*)wbf;            // n-row stride 136/8 = 17
    const int arow = wv * 16 + l15;

    f32x4 C[4] = {{0,0,0,0}, {0,0,0,0}, {0,0,0,0}, {0,0,0,0}};
#pragma unroll
    for (int ks = 0; ks < 4; ++ks) {
        bf16x8 afr = *(const bf16x8*)&As[arow][(ks * 4 + quad) * 8];
        bf16x8 b0 = wt8[(0 * 16 + l15) * 17 + ks * 4 + quad];
        bf16x8 b1 = wt8[(1 * 16 + l15) * 17 + ks * 4 + quad];
        bf16x8 b2 = wt8[(2 * 16 + l15) * 17 + ks * 4 + quad];
        bf16x8 b3 = wt8[(3 * 16 + l15) * 17 + ks * 4 + quad];
        C[0] = __builtin_amdgcn_mfma_f32_16x16x32_bf16(afr, b0, C[0], 0, 0, 0);
        C[1] = __builtin_amdgcn_mfma_f32_16x16x32_bf16(afr, b1, C[1], 0, 0, 0);
        C[2] = __builtin_amdgcn_mfma_f32_16x16x32_bf16(afr, b2, C[2], 0, 0, 0);
        C[3] = __builtin_amdgcn_mfma_f32_16x16x32_bf16(afr, b3, C[3], 0, 0, 0);
    }

    float bias[4];
#pragma unroll
    for (int nt = 0; nt < 4; ++nt) bias[nt] = biasf[nt * 16 + l15];

    float x[4][4];
    float ss[4] = {0.f, 0.f, 0.f, 0.f};
#pragma unroll
    for (int nt = 0; nt < 4; ++nt)
#pragma unroll
        for (int rg = 0; rg < 4; ++rg) {
            float v = C[nt][rg] + bias[nt];
            v = (v >= 0.f) ? v : 0.2f * v;
            x[nt][rg] = v;
            ss[rg] = fmaf(v, v, ss[rg]);
        }
#pragma unroll
    for (int rg = 0; rg < 4; ++rg) {
        ss[rg] += __shfl_xor(ss[rg], 1);
        ss[rg] += __shfl_xor(ss[rg], 2);
        ss[rg] += __shfl_xor(ss[rg], 4);
        ss[rg] += __shfl_xor(ss[rg], 8);
    }
#pragma unroll
    for (int rg = 0; rg < 4; ++rg) {
        int row = blockIdx.x * 32 + wv * 16 + quad * 4 + rg;   // C/D: col=l15, row=quad*4+reg
        if (row >= n_rows) continue;
        float invr = 1.0f / fmaxf(sqrtf(ss[rg]), 1e-12f);
        if (out_mode) {
#pragma unroll
            for (int nt = 0; nt < 4; ++nt)
                out[(size_t)row * 256 + col0 + nt * 16 + l15] = x[nt][rg] * invr;
        } else {
#pragma unroll
            for (int nt = 0; nt < 4; ++nt)
                ego_out[(size_t)row * 64 + nt * 16 + l15] = (ushort)bf16_rne(x[nt][rg]);
            if (l15 == 0) inv_norm[row] = invr;
        }
    }
}

extern "C" void kernel_launch(void* const* d_in, const int* in_sizes, int n_in,
                              void* d_out, int out_size, void* d_ws, size_t ws_size,
                              hipStream_t stream) {
    const int* users = (const int*)d_in[0];
    const int* pos   = (const int*)d_in[1];
    const int* neg   = (const int*)d_in[2];
    const int* arow  = (const int*)d_in[3];
    const int* acol  = (const int*)d_in[4];
    const float* aval = (const float*)d_in[5];
    const float* ue   = (const float*)d_in[6];
    const float* ie   = (const float*)d_in[7];
    const float* Wgc  = (const float*)d_in[8];
    const float* bgc  = (const float*)d_in[9];
    const float* Wbi  = (const float*)d_in[10];
    const float* bbi  = (const float*)d_in[11];
    float* out = (float*)d_out;

    char* ws = (char*)d_ws;
    size_t o = 0;
    ushort* ego_a   = (ushort*)(ws + o); o += 19200000;
    ushort* ego_b   = (ushort*)(ws + o); o += 19200000;
    int2*   ecv     = (int2*)  (ws + o); o += (size_t)NB * CAP * 8;   // 21.8 MB padded
    int2*   tmp_cv  = (int2*)  (ws + o); o += (size_t)NB * CAP * 8;   // 21.8 MB padded
    int*    gcur    = (int*)   (ws + o); o += 2048;                   // 512 ints
    int2*   row_se  = (int2*)  (ws + o); o += 1200128;                // 150016 x int2
    float*  inv_a     = (float*)(ws + o); o += 600064;
    float*  inv_b     = (float*)(ws + o); o += 600064;
    int*    samp      = (int*) (ws + o); o += 49152;
    ushort* wbf       = (ushort*)(ws + o); o += 52224;           // 3 x 64 x 136 bf16
    float*  biasf     = (float*)(ws + o); o += 768;              // 3 x 64

    const int gatherBlocks = (NSAMP * EMB) / 256;                // 3072
    const int spmmN = (N_NODES + 31) / 32;                       // 4688
    const int spmmS = NSAMP / 32;                                // 384

    // ---- CSR build (+ overlapped init): memset + 1 dispatch ----
    hipMemsetAsync(gcur, 0, 2048, stream);
    scat_init<<<BS_GRID + INIT_BLOCKS, 1024, 0, stream>>>(
        arow, acol, aval, gcur, tmp_cv,
        (const float4*)ue, (const float4*)ie,
        users, pos, neg, (uint2*)ego_a, out, samp,
        Wgc, Wbi, bgc, bbi, wbf, biasf);

    // ---- bucket sort + ecv flush + LAYER 1 fused: ego_a -> ego_b ----
    csr_spmm1<<<NB, 1024, 0, stream>>>(
        gcur, tmp_cv, ecv, row_se,
        (const uint4*)ego_a, wbf, biasf, ego_b, inv_b);

    // ---- layer 2: ego_b -> ego_a  (+ piggy gather of layer-1 slice, col 64) ----
    spmm_gemm<<<spmmN + gatherBlocks, 256, 0, stream>>>(
        row_se, ecv, (const uint4*)ego_b, wbf + 8704, biasf + 64,
        ego_a, inv_a, out, nullptr, N_NODES, 0, 0,
        ego_b, inv_b, samp, 64);

    // ---- layer 3: sampled rows -> out col 192 (+ piggy gather of layer-2 slice, col 128) ----
    spmm_gemm<<<spmmS + gatherBlocks, 256, 0, stream>>>(
        row_se, ecv, (const uint4*)ego_a, wbf + 2 * 8704, biasf + 128,
        nullptr, nullptr, out, samp, NSAMP, 1, 192,
        ego_a, inv_a, samp, 128);
}

// Round 13
// 285.663 us; speedup vs baseline: 1.0510x; 1.0510x over previous
//
#include <hip/hip_runtime.h>

typedef short bf16x8 __attribute__((ext_vector_type(8)));
typedef float f32x4  __attribute__((ext_vector_type(4)));

#define N_USER 50000
#define N_ITEM 100000
#define N_NODES 150000
#define EMB 64
#define NNZ 2400000
#define BATCH 4096
#define NSAMP (3 * BATCH)     // 12288 sampled rows
#define NB 256                // row-range buckets
#define RPB 587               // rows per bucket (256*587 = 150272 >= 150000)
#define BS_GRID 500           // edge-slice blocks (NNZ/500 = 4800 exact)
#define EPB (NNZ / BS_GRID)   // 4800 edges per block
#define CAP 10304             // bucket capacity (mean 9375 + ~9.6 sigma)

// bf16 round-to-nearest-even; low 16 bits hold the bf16
__device__ __forceinline__ unsigned int bf16_rne(float x) {
    unsigned int u = __float_as_uint(x);
    return (u + 0x7fffu + ((u >> 16) & 1u)) >> 16;
}
__device__ __forceinline__ float bflo(unsigned int u) { return __uint_as_float(u << 16); }
__device__ __forceinline__ float bfhi(unsigned int u) { return __uint_as_float(u & 0xffff0000u); }

__device__ __forceinline__ void fma8(float v, const uint4& x, float* acc) {
    acc[0] = fmaf(v, bflo(x.x), acc[0]); acc[1] = fmaf(v, bfhi(x.x), acc[1]);
    acc[2] = fmaf(v, bflo(x.y), acc[2]); acc[3] = fmaf(v, bfhi(x.y), acc[3]);
    acc[4] = fmaf(v, bflo(x.z), acc[4]); acc[5] = fmaf(v, bfhi(x.z), acc[5]);
    acc[6] = fmaf(v, bflo(x.w), acc[6]); acc[7] = fmaf(v, bfhi(x.w), acc[7]);
}
__device__ __forceinline__ uint4 pack8(const float* f) {
    return make_uint4((bf16_rne(f[1]) << 16) | bf16_rne(f[0]),
                      (bf16_rne(f[3]) << 16) | bf16_rne(f[2]),
                      (bf16_rne(f[5]) << 16) | bf16_rne(f[4]),
                      (bf16_rne(f[7]) << 16) | bf16_rne(f[6]));
}
__device__ __forceinline__ uint2 cvt2(const float4& v) {
    return make_uint2((bf16_rne(v.y) << 16) | bf16_rne(v.x),
                      (bf16_rne(v.w) << 16) | bf16_rne(v.z));
}

// ==== FUSED scat_init: blocks 0..499 = LDS-sort bin_scatter (NO global atomics);
//      blocks 500.. = streaming init (ego cast / gather0 / W-pack / bias / samp) ====
#define SEG_A (N_NODES * 4)           // 600000 threads: 4x float4 -> 4x uint2 each
#define SEG_B (NSAMP * 16)            // 196608 threads: float4 gather0 each
#define SEG_C (3 * 8192)              // 24576 threads: W bf16 pack (wT[n][k], stride 136)
#define SEG_D 192                     // bias precompute
#define INIT_TOT (SEG_A + SEG_B + SEG_C + SEG_D + NSAMP)
#define INIT_BLOCKS ((INIT_TOT + 1023) / 1024)
__global__ __launch_bounds__(1024) void scat_init(const int* __restrict__ rows,
                                                  const int* __restrict__ cols,
                                                  const float* __restrict__ vals,
                                                  int* __restrict__ gcur,
                                                  int2* __restrict__ tmp_cv,
                                                  const float4* __restrict__ ue4,
                                                  const float4* __restrict__ ie4,
                                                  const int* __restrict__ users,
                                                  const int* __restrict__ pos,
                                                  const int* __restrict__ neg,
                                                  uint2* __restrict__ ego_bf,
                                                  float* __restrict__ out,
                                                  int* __restrict__ samp,
                                                  const float* __restrict__ Wgc,
                                                  const float* __restrict__ Wbi,
                                                  const float* __restrict__ bgc,
                                                  const float* __restrict__ bbi,
                                                  ushort* __restrict__ wbf,
                                                  float* __restrict__ biasf) {
    __shared__ int2 sorted[EPB];                       // 38.4 KB
    __shared__ int hist[NB];
    __shared__ int excl[NB];                           // inclusive after scan
    __shared__ int cur[NB];
    __shared__ int gb[NB];
    const int t = threadIdx.x;
    if (blockIdx.x < BS_GRID) {                        // ---- bin_scatter branch ----
        const int blk = blockIdx.x;
        if (t < NB) { hist[t] = 0; cur[t] = 0; }
        __syncthreads();
        const int e0 = blk * EPB;
        // pass A: bucket histogram
        for (int i = t; i < EPB; i += 1024) atomicAdd(&hist[rows[e0 + i] / RPB], 1);
        __syncthreads();
        // reserve global space per bucket (order across blocks arbitrary)
        if (t < NB) gb[t] = atomicAdd(&gcur[t], hist[t]);
        // scan hist -> inclusive in excl
        if (t < NB) excl[t] = hist[t];
        for (int off = 1; off < NB; off <<= 1) {
            __syncthreads();
            int add = (t < NB && t >= off) ? excl[t - off] : 0;
            __syncthreads();
            if (t < NB) excl[t] += add;
        }
        __syncthreads();
        // pass B: scatter into LDS sorted-by-bucket (rows re-read: L1-hot)
        for (int i = t; i < EPB; i += 1024) {
            int e = e0 + i;
            int r = rows[e];
            int b = r / RPB;
            int slot = atomicAdd(&cur[b], 1);
            unsigned vv = (__float_as_uint(vals[e]) & ~1023u) | (unsigned)(r - b * RPB);
            sorted[excl[b] - hist[b] + slot] = make_int2(cols[e], (int)vv);
        }
        __syncthreads();
        // pass C: full-block coalesced flush; bucket found by binary search on excl
        for (int i = t; i < EPB; i += 1024) {
            int lo = 0, hi = NB - 1;
            while (lo < hi) {                          // first b with excl[b] > i
                int mid = (lo + hi) >> 1;
                if (excl[mid] > i) hi = mid; else lo = mid + 1;
            }
            int b = lo;
            int lob = excl[b] - hist[b];
            tmp_cv[(size_t)b * CAP + gb[b] + (i - lob)] = sorted[i];
        }
        return;
    }
    // ---- streaming init branch ----
    int idx = (blockIdx.x - BS_GRID) * 1024 + t;
    if (idx >= INIT_TOT) return;
    if (idx < SEG_A) {
        const int NU4 = N_USER * 16;                   // 800000 float4s (mult of 4)
        int b4 = idx * 4;
        float4 a, b, c, d;
        if (b4 < NU4) { a = ue4[b4]; b = ue4[b4 + 1]; c = ue4[b4 + 2]; d = ue4[b4 + 3]; }
        else { int j = b4 - NU4; a = ie4[j]; b = ie4[j + 1]; c = ie4[j + 2]; d = ie4[j + 3]; }
        uint2 o0 = cvt2(a), o1 = cvt2(b), o2 = cvt2(c), o3 = cvt2(d);
        uint4* e4 = (uint4*)ego_bf;
        e4[idx * 2]     = make_uint4(o0.x, o0.y, o1.x, o1.y);
        e4[idx * 2 + 1] = make_uint4(o2.x, o2.y, o3.x, o3.y);
    } else if (idx < SEG_A + SEG_B) {
        int tt = idx - SEG_A;
        int r = tt >> 4, dq = tt & 15;
        int seg = r >> 12, bi = r & (BATCH - 1);
        int node = (seg == 0) ? users[bi] : N_USER + ((seg == 1) ? pos[bi] : neg[bi]);
        float4 v = (node < N_USER) ? ue4[node * 16 + dq] : ie4[(node - N_USER) * 16 + dq];
        ((float4*)out)[(size_t)r * 64 + dq] = v;
    } else if (idx < SEG_A + SEG_B + SEG_C) {
        int tt = idx - SEG_A - SEG_B;                  // l*8192 + k*64 + n (coalesced reads)
        int l = tt >> 13, rem = tt & 8191;
        int k = rem >> 6, n = rem & 63;
        float w = (k < 64) ? Wgc[l * 4096 + k * 64 + n] : Wbi[l * 4096 + (k - 64) * 64 + n];
        wbf[l * 8704 + n * 136 + k] = (ushort)bf16_rne(w);
    } else if (idx < SEG_A + SEG_B + SEG_C + SEG_D) {
        int tt = idx - SEG_A - SEG_B - SEG_C;
        biasf[tt] = bgc[tt] + bbi[tt];
    } else {
        int tt = idx - SEG_A - SEG_B - SEG_C - SEG_D;  // < NSAMP
        int seg = tt >> 12, bi = tt & (BATCH - 1);
        samp[tt] = (seg == 0) ? users[bi] : N_USER + ((seg == 1) ? pos[bi] : neg[bi]);
    }
}

// ======== csr_from_bins: single global read — stage bucket in LDS, sort, flush ========
__global__ __launch_bounds__(1024) void csr_from_bins(const int* __restrict__ gcur,
                                                      const int2* __restrict__ tmp_cv,
                                                      int2* __restrict__ ecv,
                                                      int2* __restrict__ row_se) {
    __shared__ int2 stage[CAP];                        // 82.4 KB (bucket payload)
    __shared__ int rcur[RPB];
    __shared__ int sc[1024];
    const int b = blockIdx.x;
    const int row0 = b * RPB;
    const int t = threadIdx.x;
    const int beg = b * CAP;
    const int cnt = gcur[b];

    if (t < RPB) rcur[t] = 0;
    __syncthreads();
    // fused load + per-row histogram (one global pass)
    for (int i = t; i < cnt; i += 1024) {
        int2 rec = tmp_cv[beg + i];
        stage[i] = rec;
        atomicAdd(&rcur[rec.y & 1023], 1);
    }
    __syncthreads();

    int v = (t < RPB) ? rcur[t] : 0;
    sc[t] = v;
    for (int off = 1; off < 1024; off <<= 1) {
        __syncthreads();
        int add = (t >= off) ? sc[t - off] : 0;
        __syncthreads();
        sc[t] += add;
    }
    __syncthreads();
    int ex = sc[t] - v;                                // exclusive prefix within bucket

    int lim = N_NODES - row0;
    if (lim > RPB) lim = RPB;
    if (t < lim) row_se[row0 + t] = make_int2(beg + ex, beg + ex + v);
    if (t < RPB) rcur[t] = ex;                         // reuse as cursor
    __syncthreads();
    // permute LDS -> ecv (writes land inside this bucket's 82 KB window: L2-resident)
    for (int i = t; i < cnt; i += 1024) {
        int2 rec = stage[i];
        int r10 = rec.y & 1023;
        int dst = beg + atomicAdd(&rcur[r10], 1);
        ecv[dst] = make_int2(rec.x, rec.y & ~1023);
    }
}

// ======== FUSED spmm + gemm (round-5 shape + 2-deep gather): 32 rows/block ========
__global__ __launch_bounds__(256) void spmm_gemm(const int2* __restrict__ row_se,
                                                 const int2* __restrict__ ecv,
                                                 const uint4* __restrict__ ego_bf, // 8 uint4/row
                                                 const ushort* __restrict__ wbf,   // [64][136] bf16
                                                 const float* __restrict__ biasf,  // [64]
                                                 ushort* __restrict__ ego_out,
                                                 float* __restrict__ inv_norm,
                                                 float* __restrict__ out,
                                                 const int* __restrict__ node_list,
                                                 int n_rows, int out_mode, int col0,
                                                 const ushort* __restrict__ g_ego,
                                                 const float* __restrict__ g_inv,
                                                 const int* __restrict__ g_samp,
                                                 int g_col0) {
    const int t = threadIdx.x;
    const int spmmBlocks = (n_rows + 31) >> 5;
    if ((int)blockIdx.x >= spmmBlocks) {               // ---- piggy slice gather ----
        int i = (blockIdx.x - spmmBlocks) * 256 + t;   // grid sized to exactly NSAMP*EMB
        int r = i >> 6, d = i & 63;
        int node = g_samp[r];
        float v = __uint_as_float(((unsigned int)g_ego[(size_t)node * 64 + d]) << 16) * g_inv[node];
        out[(size_t)r * 256 + g_col0 + d] = v;
        return;
    }

    __shared__ ushort As[32][136];                     // 8.7 KB, padded stride (272 B)

    const int d8 = t & 7;                              // dim group: dims d8*8 .. d8*8+7
    const int rl = t >> 3;                             // local row 0..31
    const int r = blockIdx.x * 32 + rl;
    const bool valid = (r < n_rows);
    const int node = valid ? (node_list ? node_list[r] : r) : 0;
    int s0 = 0, s1 = 0;
    if (valid) { int2 se = row_se[node]; s0 = se.x; s1 = se.y; }
    const uint4 selfv = ego_bf[(size_t)node * 8 + d8];
    const int lbase = (t & 63) & 56;                   // base lane of this 8-lane group

    float acc[8] = {0.f, 0.f, 0.f, 0.f, 0.f, 0.f, 0.f, 0.f};
    int2 m = make_int2(0, 0);
    if (s0 + d8 < s1) m = ecv[s0 + d8];
    for (int e0 = s0; e0 < s1; e0 += 8) {
        int2 mn = make_int2(0, 0);                     // prefetch next packet
        if (e0 + 8 + d8 < s1) mn = ecv[e0 + 8 + d8];
#pragma unroll
        for (int j = 0; j < 8; j += 2) {               // 2 gathers in flight (round-1 proven)
            int   c0 = __shfl(m.x, lbase + j);
            float v0 = __int_as_float(__shfl(m.y, lbase + j));
            int   c1 = __shfl(m.x, lbase + j + 1);
            float v1 = __int_as_float(__shfl(m.y, lbase + j + 1));
            const uint4 x0 = ego_bf[(size_t)c0 * 8 + d8];
            const uint4 x1 = ego_bf[(size_t)c1 * 8 + d8];
            fma8(v0, x0, acc);
            fma8(v1, x1, acc);
        }
        m = mn;
    }
    float cs[8] = { bflo(selfv.x) * acc[0], bfhi(selfv.x) * acc[1],
                    bflo(selfv.y) * acc[2], bfhi(selfv.y) * acc[3],
                    bflo(selfv.z) * acc[4], bfhi(selfv.z) * acc[5],
                    bflo(selfv.w) * acc[6], bfhi(selfv.w) * acc[7] };
    *(uint4*)&As[rl][d8 * 8]      = pack8(acc);        // side half (k 0..63)
    *(uint4*)&As[rl][64 + d8 * 8] = pack8(cs);         // ego*side half (k 64..127)
    __syncthreads();

    const int wv = t >> 6;
    if (wv >= 2) return;                               // waves 2,3 done (gemm tail is tiny)
    const int lane = t & 63;
    const int l15 = lane & 15, quad = lane >> 4;
    const bf16x8* wt8 = (const bf16x8*)wbf;            // n-row stride 136/8 = 17
    const int arow = wv * 16 + l15;

    f32x4 C[4] = {{0,0,0,0}, {0,0,0,0}, {0,0,0,0}, {0,0,0,0}};
#pragma unroll
    for (int ks = 0; ks < 4; ++ks) {
        bf16x8 afr = *(const bf16x8*)&As[arow][(ks * 4 + quad) * 8];
        bf16x8 b0 = wt8[(0 * 16 + l15) * 17 + ks * 4 + quad];
        bf16x8 b1 = wt8[(1 * 16 + l15) * 17 + ks * 4 + quad];
        bf16x8 b2 = wt8[(2 * 16 + l15) * 17 + ks * 4 + quad];
        bf16x8 b3 = wt8[(3 * 16 + l15) * 17 + ks * 4 + quad];
        C[0] = __builtin_amdgcn_mfma_f32_16x16x32_bf16(afr, b0, C[0], 0, 0, 0);
        C[1] = __builtin_amdgcn_mfma_f32_16x16x32_bf16(afr, b1, C[1], 0, 0, 0);
        C[2] = __builtin_amdgcn_mfma_f32_16x16x32_bf16(afr, b2, C[2], 0, 0, 0);
        C[3] = __builtin_amdgcn_mfma_f32_16x16x32_bf16(afr, b3, C[3], 0, 0, 0);
    }

    float bias[4];
#pragma unroll
    for (int nt = 0; nt < 4; ++nt) bias[nt] = biasf[nt * 16 + l15];

    float x[4][4];
    float ss[4] = {0.f, 0.f, 0.f, 0.f};
#pragma unroll
    for (int nt = 0; nt < 4; ++nt)
#pragma unroll
        for (int rg = 0; rg < 4; ++rg) {
            float v = C[nt][rg] + bias[nt];
            v = (v >= 0.f) ? v : 0.2f * v;
            x[nt][rg] = v;
            ss[rg] = fmaf(v, v, ss[rg]);
        }
#pragma unroll
    for (int rg = 0; rg < 4; ++rg) {
        ss[rg] += __shfl_xor(ss[rg], 1);
        ss[rg] += __shfl_xor(ss[rg], 2);
        ss[rg] += __shfl_xor(ss[rg], 4);
        ss[rg] += __shfl_xor(ss[rg], 8);
    }
#pragma unroll
    for (int rg = 0; rg < 4; ++rg) {
        int row = blockIdx.x * 32 + wv * 16 + quad * 4 + rg;   // C/D: col=l15, row=quad*4+reg
        if (row >= n_rows) continue;
        float invr = 1.0f / fmaxf(sqrtf(ss[rg]), 1e-12f);
        if (out_mode) {
#pragma unroll
            for (int nt = 0; nt < 4; ++nt)
                out[(size_t)row * 256 + col0 + nt * 16 + l15] = x[nt][rg] * invr;
        } else {
#pragma unroll
            for (int nt = 0; nt < 4; ++nt)
                ego_out[(size_t)row * 64 + nt * 16 + l15] = (ushort)bf16_rne(x[nt][rg]);
            if (l15 == 0) inv_norm[row] = invr;
        }
    }
}

extern "C" void kernel_launch(void* const* d_in, const int* in_sizes, int n_in,
                              void* d_out, int out_size, void* d_ws, size_t ws_size,
                              hipStream_t stream) {
    const int* users = (const int*)d_in[0];
    const int* pos   = (const int*)d_in[1];
    const int* neg   = (const int*)d_in[2];
    const int* arow  = (const int*)d_in[3];
    const int* acol  = (const int*)d_in[4];
    const float* aval = (const float*)d_in[5];
    const float* ue   = (const float*)d_in[6];
    const float* ie   = (const float*)d_in[7];
    const float* Wgc  = (const float*)d_in[8];
    const float* bgc  = (const float*)d_in[9];
    const float* Wbi  = (const float*)d_in[10];
    const float* bbi  = (const float*)d_in[11];
    float* out = (float*)d_out;

    char* ws = (char*)d_ws;
    size_t o = 0;
    ushort* ego_a   = (ushort*)(ws + o); o += 19200000;
    ushort* ego_b   = (ushort*)(ws + o); o += 19200000;
    int2*   ecv     = (int2*)  (ws + o); o += (size_t)NB * CAP * 8;   // 21.1 MB padded
    int2*   tmp_cv  = (int2*)  (ws + o); o += (size_t)NB * CAP * 8;   // 21.1 MB padded
    int*    gcur    = (int*)   (ws + o); o += 1024;                   // 256 ints (+pad)
    int2*   row_se  = (int2*)  (ws + o); o += 1200128;
    float*  inv_a     = (float*)(ws + o); o += 600064;
    float*  inv_b     = (float*)(ws + o); o += 600064;
    int*    samp      = (int*) (ws + o); o += 49152;
    ushort* wbf       = (ushort*)(ws + o); o += 52224;           // 3 x 64 x 136 bf16
    float*  biasf     = (float*)(ws + o); o += 768;              // 3 x 64

    const int gatherBlocks = (NSAMP * EMB) / 256;                // 3072
    const int spmmN = (N_NODES + 31) / 32;                       // 4688
    const int spmmS = NSAMP / 32;                                // 384

    // ---- CSR build (+ overlapped init): memset + 2 dispatches ----
    hipMemsetAsync(gcur, 0, 1024, stream);
    scat_init<<<BS_GRID + INIT_BLOCKS, 1024, 0, stream>>>(
        arow, acol, aval, gcur, tmp_cv,
        (const float4*)ue, (const float4*)ie,
        users, pos, neg, (uint2*)ego_a, out, samp,
        Wgc, Wbi, bgc, bbi, wbf, biasf);
    csr_from_bins<<<NB, 1024, 0, stream>>>(gcur, tmp_cv, ecv, row_se);

    // ---- layer 1: ego_a -> ego_b ----
    spmm_gemm<<<spmmN, 256, 0, stream>>>(
        row_se, ecv, (const uint4*)ego_a, wbf, biasf,
        ego_b, inv_b, out, nullptr, N_NODES, 0, 0,
        nullptr, nullptr, nullptr, 0);

    // ---- layer 2: ego_b -> ego_a  (+ piggy gather of layer-1 slice, col 64) ----
    spmm_gemm<<<spmmN + gatherBlocks, 256, 0, stream>>>(
        row_se, ecv, (const uint4*)ego_b, wbf + 8704, biasf + 64,
        ego_a, inv_a, out, nullptr, N_NODES, 0, 0,
        ego_b, inv_b, samp, 64);

    // ---- layer 3: sampled rows -> out col 192 (+ piggy gather of layer-2 slice, col 128) ----
    spmm_gemm<<<spmmS + gatherBlocks, 256, 0, stream>>>(
        row_se, ecv, (const uint4*)ego_a, wbf + 2 * 8704, biasf + 128,
        nullptr, nullptr, out, samp, NSAMP, 1, 192,
        ego_a, inv_a, samp, 128);
}